// Round 3
// baseline (352.704 us; speedup 1.0000x reference)
//
#include <hip/hip_runtime.h>

typedef __bf16 bf16x8 __attribute__((ext_vector_type(8)));
typedef __bf16 bf16x4 __attribute__((ext_vector_type(4)));
typedef float f32x4 __attribute__((ext_vector_type(4)));

__device__ __forceinline__ f32x4 mfma16(bf16x8 a, bf16x8 b, f32x4 c) {
  return __builtin_amdgcn_mfma_f32_16x16x32_bf16(a, b, c, 0, 0, 0);
}

// ---- fp32 -> bf16 pre-convert: x (4096 blks), qkv_w (1536), out_w (512) ----
__global__ __launch_bounds__(256) void convert3(
    const float* __restrict__ x, const float* __restrict__ w1,
    const float* __restrict__ w2, __bf16* __restrict__ xb,
    __bf16* __restrict__ w1b, __bf16* __restrict__ w2b) {
  int bid = blockIdx.x;
  const float* src;
  __bf16* dst;
  int base;
  if (bid < 4096) {
    src = x; dst = xb; base = bid;
  } else if (bid < 5632) {
    src = w1; dst = w1b; base = bid - 4096;
  } else {
    src = w2; dst = w2b; base = bid - 5632;
  }
  size_t off = (size_t)base * 2048 + threadIdx.x * 8;
  float4 v0 = *(const float4*)(src + off);
  float4 v1 = *(const float4*)(src + off + 4);
  bf16x8 o = {(__bf16)v0.x, (__bf16)v0.y, (__bf16)v0.z, (__bf16)v0.w,
              (__bf16)v1.x, (__bf16)v1.y, (__bf16)v1.z, (__bf16)v1.w};
  *(bf16x8*)(dst + off) = o;
}

// C[M][N] = A[M][K] @ B[N][K]^T + bias[N]; A,B bf16; C bf16 or fp32.
// Block 256 (4 waves), tile 128x128, BK=32, register-prefetch double buffer.
template <bool C_BF16>
__global__ __launch_bounds__(256) void gemm_bt(
    const __bf16* __restrict__ A, const __bf16* __restrict__ B,
    const float* __restrict__ bias, void* __restrict__ Cv, int M, int N,
    int K) {
  constexpr int LDA = 40;
  __shared__ __bf16 As[128 * LDA];
  __shared__ __bf16 Bs[128 * LDA];

  const int tid = threadIdx.x;
  const int wid = tid >> 6;
  const int lane = tid & 63;
  const int l15 = lane & 15;
  const int quad = lane >> 4;
  const int bm = blockIdx.y * 128;
  const int bn = blockIdx.x * 128;
  const int wm = (wid & 1) * 64;
  const int wn = (wid >> 1) * 64;

  f32x4 acc[4][4] = {};

  // staging coords: chunk id = p*256+tid -> row id>>2, 16B-chunk id&3
  int r0 = tid >> 2, c0 = tid & 3;
  int r1 = (256 + tid) >> 2, c1 = tid & 3;  // p=1: rows 64..127

  bf16x8 pa[2], pb[2];
  pa[0] = *(const bf16x8*)(A + (size_t)(bm + r0) * K + c0 * 8);
  pa[1] = *(const bf16x8*)(A + (size_t)(bm + r1) * K + c1 * 8);
  pb[0] = *(const bf16x8*)(B + (size_t)(bn + r0) * K + c0 * 8);
  pb[1] = *(const bf16x8*)(B + (size_t)(bn + r1) * K + c1 * 8);

  const int niter = K >> 5;
  for (int it = 0; it < niter; ++it) {
    __syncthreads();  // previous iter's readers done
    *(bf16x8*)(As + r0 * LDA + c0 * 8) = pa[0];
    *(bf16x8*)(As + r1 * LDA + c1 * 8) = pa[1];
    *(bf16x8*)(Bs + r0 * LDA + c0 * 8) = pb[0];
    *(bf16x8*)(Bs + r1 * LDA + c1 * 8) = pb[1];
    if (it + 1 < niter) {
      int k0 = (it + 1) << 5;
      pa[0] = *(const bf16x8*)(A + (size_t)(bm + r0) * K + k0 + c0 * 8);
      pa[1] = *(const bf16x8*)(A + (size_t)(bm + r1) * K + k0 + c1 * 8);
      pb[0] = *(const bf16x8*)(B + (size_t)(bn + r0) * K + k0 + c0 * 8);
      pb[1] = *(const bf16x8*)(B + (size_t)(bn + r1) * K + k0 + c1 * 8);
    }
    __syncthreads();

    bf16x8 af[4], bf[4];
#pragma unroll
    for (int i = 0; i < 4; ++i)
      af[i] = *(const bf16x8*)(As + (wm + i * 16 + l15) * LDA + quad * 8);
#pragma unroll
    for (int i = 0; i < 4; ++i)
      bf[i] = *(const bf16x8*)(Bs + (wn + i * 16 + l15) * LDA + quad * 8);
#pragma unroll
    for (int mt = 0; mt < 4; ++mt)
#pragma unroll
      for (int nt = 0; nt < 4; ++nt)
        acc[mt][nt] = mfma16(af[mt], bf[nt], acc[mt][nt]);
  }

#pragma unroll
  for (int mt = 0; mt < 4; ++mt) {
#pragma unroll
    for (int nt = 0; nt < 4; ++nt) {
      int gc = bn + wn + nt * 16 + l15;
      float bv = bias[gc];
#pragma unroll
      for (int r = 0; r < 4; ++r) {
        int gr = bm + wm + mt * 16 + quad * 4 + r;
        float val = acc[mt][nt][r] + bv;
        if constexpr (C_BF16)
          ((__bf16*)Cv)[(size_t)gr * N + gc] = (__bf16)val;
        else
          ((float*)Cv)[(size_t)gr * N + gc] = val;
      }
    }
  }
}

// Flash attention, causal. qkv: (B*T, 3072) bf16; out: (B*T, 1024) bf16.
// Grid (64 bh, 16 pb), block 128 = 2 waves, BQ=64 (32 rows/wave), BKV=64.
// bh fastest => the 16 blocks sharing a bh sit on one XCD (KV L2-resident).
// Block pb handles q-tiles {pb, 31-pb}: uniform 33 kv-iters.
// XOR-swizzled unpadded LDS; no-max softmax (bounded scores), deferred l.
__global__ __launch_bounds__(128) void attn_kernel(
    const __bf16* __restrict__ qkv, __bf16* __restrict__ out) {
  constexpr int T = 2048, C3 = 3072;
  __shared__ __bf16 Ks[2][64 * 64];  // [kv][d], octet-swizzled
  __shared__ __bf16 Vt[2][64 * 64];  // [d][kv], octet-swizzled
  __shared__ __bf16 Ps[2][32 * 64];  // per-wave P [qrow][kv], octet-swizzled

  const int tid = threadIdx.x;
  const int wid = tid >> 6;
  const int lane = tid & 63;
  const int l15 = lane & 15;
  const int quad = lane >> 4;
  const int bh = blockIdx.x;  // 0..63
  const int pb = blockIdx.y;  // 0..15
  const int b = bh >> 4, h = bh & 15;
  const size_t rowbase = (size_t)b * T;
  const float CE = 0.18033688011112043f;  // log2(e)/8

  const int sr = tid >> 3;  // 0..15
  const int sc = tid & 7;   // d-octet

#pragma unroll 1
  for (int phase = 0; phase < 2; ++phase) {
    const int qp = phase == 0 ? pb : 31 - pb;
    const int q0 = qp * 64;
    const int ntiles = qp + 1;

    bf16x8 qf[2][2];
#pragma unroll
    for (int mt = 0; mt < 2; ++mt)
#pragma unroll
      for (int ksi = 0; ksi < 2; ++ksi)
        qf[mt][ksi] = *(const bf16x8*)(
            qkv + (rowbase + q0 + wid * 32 + mt * 16 + l15) * C3 + h * 64 +
            ksi * 32 + quad * 8);

    f32x4 acc[2][4] = {};
    float lsum[2][4] = {};

    // prefetch tile 0
    bf16x8 kreg[4], vreg[4];
#pragma unroll
    for (int p = 0; p < 4; ++p)
      kreg[p] = *(const bf16x8*)(qkv + (rowbase + p * 16 + sr) * C3 + 1024 +
                                 h * 64 + sc * 8);
#pragma unroll
    for (int i = 0; i < 4; ++i)
      vreg[i] = *(const bf16x8*)(qkv + (rowbase + 4 * sr + i) * C3 + 2048 +
                                 h * 64 + sc * 8);

    __syncthreads();  // previous phase's readers done

    for (int j = 0; j < ntiles; ++j) {
      __bf16* ksb = Ks[j & 1];
      __bf16* vtb = Vt[j & 1];
      // ---- LDS store of prefetched tile ----
#pragma unroll
      for (int p = 0; p < 4; ++p) {
        int r = p * 16 + sr;
        *(bf16x8*)(ksb + r * 64 + ((sc ^ (r & 7)) * 8)) = kreg[p];
      }
#pragma unroll
      for (int jj = 0; jj < 8; ++jj) {
        int d = sc * 8 + jj;
        int g = (sr >> 1) ^ jj;  // octet (sr>>1) swizzled by d&7==jj
        bf16x4 q4 = {vreg[0][jj], vreg[1][jj], vreg[2][jj], vreg[3][jj]};
        *(bf16x4*)(vtb + d * 64 + (g & 7) * 8 + 4 * (sr & 1)) = q4;
      }
      // ---- prefetch next tile ----
      if (j + 1 < ntiles) {
        int kv0n = (j + 1) * 64;
#pragma unroll
        for (int p = 0; p < 4; ++p)
          kreg[p] = *(const bf16x8*)(qkv + (rowbase + kv0n + p * 16 + sr) * C3 +
                                     1024 + h * 64 + sc * 8);
#pragma unroll
        for (int i = 0; i < 4; ++i)
          vreg[i] = *(const bf16x8*)(qkv + (rowbase + kv0n + 4 * sr + i) * C3 +
                                     2048 + h * 64 + sc * 8);
      }
      __syncthreads();

      const int kv0 = j * 64;
      // ---- S = Q K^T ----
      f32x4 s[2][4] = {};
#pragma unroll
      for (int nt = 0; nt < 4; ++nt) {
        int krow = nt * 16 + l15;
#pragma unroll
        for (int ksi = 0; ksi < 2; ++ksi) {
          bf16x8 kf = *(const bf16x8*)(
              ksb + krow * 64 + (((4 * ksi + quad) ^ (l15 & 7)) * 8));
#pragma unroll
          for (int mt = 0; mt < 2; ++mt)
            s[mt][nt] = mfma16(qf[mt][ksi], kf, s[mt][nt]);
        }
      }
      // ---- exp, l-accumulate, P store ----
      const bool need_mask = (kv0 + 63) > (q0 + wid * 32);
#pragma unroll
      for (int mt = 0; mt < 2; ++mt) {
#pragma unroll
        for (int nt = 0; nt < 4; ++nt) {
          int kcol = kv0 + nt * 16 + l15;
#pragma unroll
          for (int r = 0; r < 4; ++r) {
            int prow = mt * 16 + quad * 4 + r;
            float p = exp2f(s[mt][nt][r] * CE);
            if (need_mask && kcol > (q0 + wid * 32 + prow)) p = 0.f;
            lsum[mt][r] += p;
            int gc = ((2 * nt + (l15 >> 3)) ^ (prow & 7)) & 7;
            Ps[wid][prow * 64 + gc * 8 + (l15 & 7)] = (__bf16)p;
          }
        }
      }
      // ---- O += P V (per-wave Ps: no barrier) ----
#pragma unroll
      for (int ksi = 0; ksi < 2; ++ksi) {
        bf16x8 pf[2];
#pragma unroll
        for (int mt = 0; mt < 2; ++mt) {
          int prow = mt * 16 + l15;
          pf[mt] = *(const bf16x8*)(
              Ps[wid] + prow * 64 + (((4 * ksi + quad) ^ (l15 & 7)) * 8));
        }
#pragma unroll
        for (int ntv = 0; ntv < 4; ++ntv) {
          int d = ntv * 16 + l15;
          bf16x8 vf = *(const bf16x8*)(
              vtb + d * 64 + ((((4 * ksi + quad) ^ (d & 7)) & 7) * 8));
#pragma unroll
          for (int mt = 0; mt < 2; ++mt)
            acc[mt][ntv] = mfma16(pf[mt], vf, acc[mt][ntv]);
        }
      }
    }

    // ---- phase epilogue ----
#pragma unroll
    for (int mt = 0; mt < 2; ++mt)
#pragma unroll
      for (int r = 0; r < 4; ++r) {
        float l = lsum[mt][r];
        l += __shfl_xor(l, 1);
        l += __shfl_xor(l, 2);
        l += __shfl_xor(l, 4);
        l += __shfl_xor(l, 8);
        float inv = 1.0f / l;
        int row = q0 + wid * 32 + mt * 16 + quad * 4 + r;
        size_t ob = (rowbase + row) * 1024 + h * 64;
#pragma unroll
        for (int ntv = 0; ntv < 4; ++ntv)
          out[ob + ntv * 16 + l15] = (__bf16)(acc[mt][ntv][r] * inv);
      }
  }
}

extern "C" void kernel_launch(void* const* d_in, const int* in_sizes, int n_in,
                              void* d_out, int out_size, void* d_ws,
                              size_t ws_size, hipStream_t stream) {
  const float* x = (const float*)d_in[0];
  const float* qkv_w = (const float*)d_in[1];
  const float* qkv_b = (const float*)d_in[2];
  const float* out_w = (const float*)d_in[3];
  const float* out_b = (const float*)d_in[4];
  float* out = (float*)d_out;

  // ws layout (bf16 elements)
  __bf16* qkv_ws = (__bf16*)d_ws;                         // 8192*3072
  __bf16* attn_ws = qkv_ws + (size_t)8192 * 3072;         // 8192*1024
  __bf16* xb = attn_ws + (size_t)8192 * 1024;             // 8192*1024
  __bf16* wqb = xb + (size_t)8192 * 1024;                 // 3072*1024
  __bf16* wob = wqb + (size_t)3072 * 1024;                // 1024*1024

  convert3<<<6144, 256, 0, stream>>>(x, qkv_w, out_w, xb, wqb, wob);
  gemm_bt<true><<<dim3(24, 64), 256, 0, stream>>>(xb, wqb, qkv_b, qkv_ws,
                                                  8192, 3072, 1024);
  attn_kernel<<<dim3(64, 16), 128, 0, stream>>>(qkv_ws, attn_ws);
  gemm_bt<false><<<dim3(8, 64), 256, 0, stream>>>(attn_ws, wob, out_b, out,
                                                  8192, 1024, 1024);
}

// Round 4
// 269.806 us; speedup vs baseline: 1.3072x; 1.3072x over previous
//
#include <hip/hip_runtime.h>

typedef __bf16 bf16x8 __attribute__((ext_vector_type(8)));
typedef __bf16 bf16x4 __attribute__((ext_vector_type(4)));
typedef float f32x4 __attribute__((ext_vector_type(4)));

typedef const __attribute__((address_space(1))) void* gptr_t;
typedef __attribute__((address_space(3))) void* lptr_t;

__device__ __forceinline__ f32x4 mfma16(bf16x8 a, bf16x8 b, f32x4 c) {
  return __builtin_amdgcn_mfma_f32_16x16x32_bf16(a, b, c, 0, 0, 0);
}

// async global->LDS, 16B per lane; lds dest = wave-uniform base + lane*16
__device__ __forceinline__ void load_lds16(const __bf16* g, __bf16* l) {
  __builtin_amdgcn_global_load_lds((gptr_t)g, (lptr_t)l, 16, 0, 0);
}

// ---- fp32 -> bf16 pre-convert: x (4096 blks), qkv_w (1536), out_w (512) ----
__global__ __launch_bounds__(256) void convert3(
    const float* __restrict__ x, const float* __restrict__ w1,
    const float* __restrict__ w2, __bf16* __restrict__ xb,
    __bf16* __restrict__ w1b, __bf16* __restrict__ w2b) {
  int bid = blockIdx.x;
  const float* src;
  __bf16* dst;
  int base;
  if (bid < 4096) {
    src = x; dst = xb; base = bid;
  } else if (bid < 5632) {
    src = w1; dst = w1b; base = bid - 4096;
  } else {
    src = w2; dst = w2b; base = bid - 5632;
  }
  size_t off = (size_t)base * 2048 + threadIdx.x * 8;
  float4 v0 = *(const float4*)(src + off);
  float4 v1 = *(const float4*)(src + off + 4);
  bf16x8 o = {(__bf16)v0.x, (__bf16)v0.y, (__bf16)v0.z, (__bf16)v0.w,
              (__bf16)v1.x, (__bf16)v1.y, (__bf16)v1.z, (__bf16)v1.w};
  *(bf16x8*)(dst + off) = o;
}

// C[M][N] = A[M][K] @ B[N][K]^T + bias[N]; A,B bf16; C bf16 or fp32.
// m97 pattern: 128x128 tile, BK=32, unpadded LDS, global_load_lds width=16,
// LDS double-buffer, one barrier/iter.
template <bool C_BF16>
__global__ __launch_bounds__(256) void gemm_bt(
    const __bf16* __restrict__ A, const __bf16* __restrict__ B,
    const float* __restrict__ bias, void* __restrict__ Cv, int M, int N,
    int K) {
  __shared__ __bf16 As[2][128 * 32];
  __shared__ __bf16 Bs[2][128 * 32];

  const int tid = threadIdx.x;
  const int wid = tid >> 6;
  const int lane = tid & 63;
  const int l15 = lane & 15;
  const int quad = lane >> 4;
  const int bm = blockIdx.y * 128;
  const int bn = blockIdx.x * 128;
  const int wm = (wid & 1) * 64;
  const int wn = (wid >> 1) * 64;

  // wave w stages rows [p*64 + w*16 .. +15]; lane l -> row +(l>>2), chunk l&3.
  // LDS linear offset for lane l is exactly base + 8*l elements (16B*l).
  const int srow = wid * 16 + (lane >> 2);
  const int schunk = (lane & 3) * 8;
  const __bf16* gA = A + (size_t)(bm + srow) * K + schunk;
  const __bf16* gB = B + (size_t)(bn + srow) * K + schunk;
  const int ldsoff = wid * 16 * 32;  // wave-uniform

  f32x4 acc[4][4] = {};

  load_lds16(gA, &As[0][ldsoff]);
  load_lds16(gA + (size_t)64 * K, &As[0][64 * 32 + ldsoff]);
  load_lds16(gB, &Bs[0][ldsoff]);
  load_lds16(gB + (size_t)64 * K, &Bs[0][64 * 32 + ldsoff]);

  const int niter = K >> 5;
  for (int it = 0; it < niter; ++it) {
    const int cur = it & 1;
    __syncthreads();  // drains vmcnt -> buf[cur] ready; buf[1-cur] readers done
    if (it + 1 < niter) {
      int k0 = (it + 1) << 5;
      load_lds16(gA + k0, &As[1 - cur][ldsoff]);
      load_lds16(gA + k0 + (size_t)64 * K, &As[1 - cur][64 * 32 + ldsoff]);
      load_lds16(gB + k0, &Bs[1 - cur][ldsoff]);
      load_lds16(gB + k0 + (size_t)64 * K, &Bs[1 - cur][64 * 32 + ldsoff]);
    }
    bf16x8 af[4], bf[4];
#pragma unroll
    for (int i = 0; i < 4; ++i)
      af[i] = *(const bf16x8*)(&As[cur][(wm + i * 16 + l15) * 32 + quad * 8]);
#pragma unroll
    for (int i = 0; i < 4; ++i)
      bf[i] = *(const bf16x8*)(&Bs[cur][(wn + i * 16 + l15) * 32 + quad * 8]);
#pragma unroll
    for (int mt = 0; mt < 4; ++mt)
#pragma unroll
      for (int nt = 0; nt < 4; ++nt)
        acc[mt][nt] = mfma16(af[mt], bf[nt], acc[mt][nt]);
  }

#pragma unroll
  for (int mt = 0; mt < 4; ++mt) {
#pragma unroll
    for (int nt = 0; nt < 4; ++nt) {
      int gc = bn + wn + nt * 16 + l15;
      float bv = bias[gc];
#pragma unroll
      for (int r = 0; r < 4; ++r) {
        int gr = bm + wm + mt * 16 + quad * 4 + r;
        float val = acc[mt][nt][r] + bv;
        if constexpr (C_BF16)
          ((__bf16*)Cv)[(size_t)gr * N + gc] = (__bf16)val;
        else
          ((float*)Cv)[(size_t)gr * N + gc] = val;
      }
    }
  }
}

// Flash attention, causal. qkv: (B*T, 3072) bf16; out: (B*T, 1024) bf16.
// Grid (64 bh, 8 pb) bh-fastest: 16 blocks/bh on one XCD (KV L2-resident).
// Block 256 = 4 waves, BQ=128, BKV=64; phases {pb, 15-pb} -> 34 iters/block.
// P/V contraction k-index permuted by pi(k)=4*(k&15)+(k>>4): P-store becomes
// 8x ds_write_b64, V staged as packed bf16x4. XOR octet swizzles keep all
// LDS accesses bank-uniform. No-max softmax (bounded scores), deferred l.
__global__ __launch_bounds__(256) void attn_kernel(
    const __bf16* __restrict__ qkv, __bf16* __restrict__ out) {
  constexpr int T = 2048, C3 = 3072;
  __shared__ __bf16 Ks[2][64 * 64];  // [kv][d]
  __shared__ __bf16 Vt[2][64 * 64];  // [d][pi(kv)]
  __shared__ __bf16 Ps[4][32 * 64];  // per-wave [qrow][pi(kv)]

  const int tid = threadIdx.x;
  const int wid = tid >> 6;
  const int lane = tid & 63;
  const int l15 = lane & 15;
  const int quad = lane >> 4;
  const int bh = blockIdx.x;  // 0..63 (fastest -> XCD-consistent)
  const int pb = blockIdx.y;  // 0..7
  const int b = bh >> 4, h = bh & 15;
  const size_t rowbase = (size_t)b * T;
  const float CE = 0.18033688011112043f;  // log2(e)/8

  const int kr = tid >> 3;  // K staging: rows kr, kr+32
  const int kc = tid & 7;   // d-octet
  const int vj = tid >> 4;  // V staging: rows vj+16i -> pi-cols 4vj+i
  const int vn = tid & 15;  // d-nibble

#pragma unroll 1
  for (int phase = 0; phase < 2; ++phase) {
    const int qp = phase == 0 ? pb : 15 - pb;
    const int q0 = qp * 128;
    const int ntiles = 2 * qp + 2;

    bf16x8 qf[2][2];
#pragma unroll
    for (int mt = 0; mt < 2; ++mt)
#pragma unroll
      for (int ksi = 0; ksi < 2; ++ksi)
        qf[mt][ksi] = *(const bf16x8*)(
            qkv + (rowbase + q0 + wid * 32 + mt * 16 + l15) * C3 + h * 64 +
            ksi * 32 + quad * 8);

    f32x4 acc[2][4] = {};
    float lsum[2][4] = {};

    // prefetch tile 0 into registers
    bf16x8 kreg[2];
    bf16x4 vreg[4];
#pragma unroll
    for (int p = 0; p < 2; ++p)
      kreg[p] = *(const bf16x8*)(qkv + (rowbase + p * 32 + kr) * C3 + 1024 +
                                 h * 64 + kc * 8);
#pragma unroll
    for (int i = 0; i < 4; ++i)
      vreg[i] = *(const bf16x4*)(qkv + (rowbase + vj + 16 * i) * C3 + 2048 +
                                 h * 64 + vn * 4);

    __syncthreads();  // previous phase's readers done

    for (int j = 0; j < ntiles; ++j) {
      __bf16* ksb = Ks[j & 1];
      __bf16* vtb = Vt[j & 1];
      // ---- LDS store of prefetched tile ----
#pragma unroll
      for (int p = 0; p < 2; ++p) {
        int r = p * 32 + kr;
        *(bf16x8*)(ksb + r * 64 + ((kc ^ (r & 7)) * 8)) = kreg[p];
      }
#pragma unroll
      for (int dd = 0; dd < 4; ++dd) {
        int d = 4 * vn + dd;
        bf16x4 t = {vreg[0][dd], vreg[1][dd], vreg[2][dd], vreg[3][dd]};
        int o = ((vj >> 1) ^ (d & 7) ^ (d >> 3)) & 7;
        *(bf16x4*)(vtb + d * 64 + o * 8 + 4 * (vj & 1)) = t;
      }
      // ---- prefetch next tile ----
      if (j + 1 < ntiles) {
        int kv0n = (j + 1) * 64;
#pragma unroll
        for (int p = 0; p < 2; ++p)
          kreg[p] = *(const bf16x8*)(qkv + (rowbase + kv0n + p * 32 + kr) * C3 +
                                     1024 + h * 64 + kc * 8);
#pragma unroll
        for (int i = 0; i < 4; ++i)
          vreg[i] = *(const bf16x4*)(qkv + (rowbase + kv0n + vj + 16 * i) * C3 +
                                     2048 + h * 64 + vn * 4);
      }
      __syncthreads();

      const int kv0 = j * 64;
      // ---- S = Q K^T ----
      f32x4 s[2][4] = {};
#pragma unroll
      for (int nt = 0; nt < 4; ++nt) {
        int krow = nt * 16 + l15;
#pragma unroll
        for (int ksi = 0; ksi < 2; ++ksi) {
          bf16x8 kf = *(const bf16x8*)(
              ksb + krow * 64 + (((4 * ksi + quad) ^ (l15 & 7)) * 8));
#pragma unroll
          for (int mt = 0; mt < 2; ++mt)
            s[mt][nt] = mfma16(qf[mt][ksi], kf, s[mt][nt]);
        }
      }
      // ---- exp, l-accumulate, packed P store (pi layout) ----
      const bool need_mask = (kv0 + 63) > (q0 + wid * 32);
#pragma unroll
      for (int mt = 0; mt < 2; ++mt) {
#pragma unroll
        for (int r = 0; r < 4; ++r) {
          int prow = mt * 16 + quad * 4 + r;
          int qrow = q0 + wid * 32 + prow;
          bf16x4 pv;
#pragma unroll
          for (int nt = 0; nt < 4; ++nt) {
            float p = exp2f(s[mt][nt][r] * CE);
            if (need_mask && (kv0 + nt * 16 + l15) > qrow) p = 0.f;
            lsum[mt][r] += p;
            pv[nt] = (__bf16)p;
          }
          int o = ((l15 >> 1) ^ (prow & 7)) & 7;
          *(bf16x4*)(Ps[wid] + prow * 64 + o * 8 + 4 * (l15 & 1)) = pv;
        }
      }
      // ---- O += P V (per-wave Ps: no barrier) ----
#pragma unroll
      for (int ksi = 0; ksi < 2; ++ksi) {
        bf16x8 pf[2];
#pragma unroll
        for (int mt = 0; mt < 2; ++mt) {
          int prow = mt * 16 + l15;
          pf[mt] = *(const bf16x8*)(
              Ps[wid] + prow * 64 + (((4 * ksi + quad) ^ (l15 & 7)) * 8));
        }
#pragma unroll
        for (int ntv = 0; ntv < 4; ++ntv) {
          int d = ntv * 16 + l15;
          int o = ((4 * ksi + quad) ^ (d & 7) ^ (d >> 3)) & 7;
          bf16x8 vf = *(const bf16x8*)(vtb + d * 64 + o * 8);
#pragma unroll
          for (int mt = 0; mt < 2; ++mt)
            acc[mt][ntv] = mfma16(pf[mt], vf, acc[mt][ntv]);
        }
      }
    }

    // ---- phase epilogue: reduce l, normalize, store ----
#pragma unroll
    for (int mt = 0; mt < 2; ++mt)
#pragma unroll
      for (int r = 0; r < 4; ++r) {
        float l = lsum[mt][r];
        l += __shfl_xor(l, 1);
        l += __shfl_xor(l, 2);
        l += __shfl_xor(l, 4);
        l += __shfl_xor(l, 8);
        float inv = 1.0f / l;
        int row = q0 + wid * 32 + mt * 16 + quad * 4 + r;
        size_t ob = (rowbase + row) * 1024 + h * 64;
#pragma unroll
        for (int ntv = 0; ntv < 4; ++ntv)
          out[ob + ntv * 16 + l15] = (__bf16)(acc[mt][ntv][r] * inv);
      }
  }
}

extern "C" void kernel_launch(void* const* d_in, const int* in_sizes, int n_in,
                              void* d_out, int out_size, void* d_ws,
                              size_t ws_size, hipStream_t stream) {
  const float* x = (const float*)d_in[0];
  const float* qkv_w = (const float*)d_in[1];
  const float* qkv_b = (const float*)d_in[2];
  const float* out_w = (const float*)d_in[3];
  const float* out_b = (const float*)d_in[4];
  float* out = (float*)d_out;

  __bf16* qkv_ws = (__bf16*)d_ws;                  // 8192*3072
  __bf16* attn_ws = qkv_ws + (size_t)8192 * 3072;  // 8192*1024
  __bf16* xb = attn_ws + (size_t)8192 * 1024;      // 8192*1024
  __bf16* wqb = xb + (size_t)8192 * 1024;          // 3072*1024
  __bf16* wob = wqb + (size_t)3072 * 1024;         // 1024*1024

  convert3<<<6144, 256, 0, stream>>>(x, qkv_w, out_w, xb, wqb, wob);
  gemm_bt<true><<<dim3(24, 64), 256, 0, stream>>>(xb, wqb, qkv_b, qkv_ws,
                                                  8192, 3072, 1024);
  attn_kernel<<<dim3(64, 8), 256, 0, stream>>>(qkv_ws, attn_ws);
  gemm_bt<false><<<dim3(8, 64), 256, 0, stream>>>(attn_ws, wob, out_b, out,
                                                  8192, 1024, 1024);
}

// Round 5
// 246.000 us; speedup vs baseline: 1.4338x; 1.0968x over previous
//
#include <hip/hip_runtime.h>

typedef __bf16 bf16x8 __attribute__((ext_vector_type(8)));
typedef __bf16 bf16x4 __attribute__((ext_vector_type(4)));
typedef float f32x4 __attribute__((ext_vector_type(4)));

typedef const __attribute__((address_space(1))) void* gptr_t;
typedef __attribute__((address_space(3))) void* lptr_t;

__device__ __forceinline__ f32x4 mfma16(bf16x8 a, bf16x8 b, f32x4 c) {
  return __builtin_amdgcn_mfma_f32_16x16x32_bf16(a, b, c, 0, 0, 0);
}

__device__ __forceinline__ void load_lds16(const __bf16* g, __bf16* l) {
  __builtin_amdgcn_global_load_lds((gptr_t)g, (lptr_t)l, 16, 0, 0);
}

__device__ __forceinline__ float fast_exp2(float x) {
#if __has_builtin(__builtin_amdgcn_exp2f)
  return __builtin_amdgcn_exp2f(x);  // raw v_exp_f32
#else
  return exp2f(x);
#endif
}

// round-to-nearest(+away) f32->bf16 for two values, packed into one dword
__device__ __forceinline__ unsigned pack_bf16(float f0, float f1) {
  unsigned u0 = __builtin_bit_cast(unsigned, f0) + 0x8000u;
  unsigned u1 = __builtin_bit_cast(unsigned, f1) + 0x8000u;
  // result bytes [f0.hi16, f1.hi16]: src0=u1 (bytes 4-7), src1=u0 (bytes 0-3)
  return __builtin_amdgcn_perm(u1, u0, 0x07060302);
}

// ---- fp32 -> bf16 pre-convert: x (4096 blks), qkv_w (1536), out_w (512) ----
__global__ __launch_bounds__(256) void convert3(
    const float* __restrict__ x, const float* __restrict__ w1,
    const float* __restrict__ w2, __bf16* __restrict__ xb,
    __bf16* __restrict__ w1b, __bf16* __restrict__ w2b) {
  int bid = blockIdx.x;
  const float* src;
  __bf16* dst;
  int base;
  if (bid < 4096) {
    src = x; dst = xb; base = bid;
  } else if (bid < 5632) {
    src = w1; dst = w1b; base = bid - 4096;
  } else {
    src = w2; dst = w2b; base = bid - 5632;
  }
  size_t off = (size_t)base * 2048 + threadIdx.x * 8;
  float4 v0 = *(const float4*)(src + off);
  float4 v1 = *(const float4*)(src + off + 4);
  bf16x8 o = {(__bf16)v0.x, (__bf16)v0.y, (__bf16)v0.z, (__bf16)v0.w,
              (__bf16)v1.x, (__bf16)v1.y, (__bf16)v1.z, (__bf16)v1.w};
  *(bf16x8*)(dst + off) = o;
}

// C[M][N] = A[M][K] @ B[N][K]^T + bias[N]; A,B bf16; C bf16 or fp32.
// m97 pattern: 128x128 tile, BK=32, unpadded LDS, global_load_lds width=16,
// LDS double-buffer, one barrier/iter. Columns < qcols get (acc+bias)*CE
// (folds the attention softmax scale into Q at zero cost).
template <bool C_BF16>
__global__ __launch_bounds__(256) void gemm_bt(
    const __bf16* __restrict__ A, const __bf16* __restrict__ B,
    const float* __restrict__ bias, void* __restrict__ Cv, int M, int N,
    int K, int qcols) {
  __shared__ __bf16 As[2][128 * 32];
  __shared__ __bf16 Bs[2][128 * 32];

  const int tid = threadIdx.x;
  const int wid = tid >> 6;
  const int lane = tid & 63;
  const int l15 = lane & 15;
  const int quad = lane >> 4;
  const int bm = blockIdx.y * 128;
  const int bn = blockIdx.x * 128;
  const int wm = (wid & 1) * 64;
  const int wn = (wid >> 1) * 64;

  const int srow = wid * 16 + (lane >> 2);
  const int schunk = (lane & 3) * 8;
  const __bf16* gA = A + (size_t)(bm + srow) * K + schunk;
  const __bf16* gB = B + (size_t)(bn + srow) * K + schunk;
  const int ldsoff = wid * 16 * 32;  // wave-uniform

  f32x4 acc[4][4] = {};

  load_lds16(gA, &As[0][ldsoff]);
  load_lds16(gA + (size_t)64 * K, &As[0][64 * 32 + ldsoff]);
  load_lds16(gB, &Bs[0][ldsoff]);
  load_lds16(gB + (size_t)64 * K, &Bs[0][64 * 32 + ldsoff]);

  const int niter = K >> 5;
  for (int it = 0; it < niter; ++it) {
    const int cur = it & 1;
    __syncthreads();
    if (it + 1 < niter) {
      int k0 = (it + 1) << 5;
      load_lds16(gA + k0, &As[1 - cur][ldsoff]);
      load_lds16(gA + k0 + (size_t)64 * K, &As[1 - cur][64 * 32 + ldsoff]);
      load_lds16(gB + k0, &Bs[1 - cur][ldsoff]);
      load_lds16(gB + k0 + (size_t)64 * K, &Bs[1 - cur][64 * 32 + ldsoff]);
    }
    bf16x8 af[4], bf[4];
#pragma unroll
    for (int i = 0; i < 4; ++i)
      af[i] = *(const bf16x8*)(&As[cur][(wm + i * 16 + l15) * 32 + quad * 8]);
#pragma unroll
    for (int i = 0; i < 4; ++i)
      bf[i] = *(const bf16x8*)(&Bs[cur][(wn + i * 16 + l15) * 32 + quad * 8]);
#pragma unroll
    for (int mt = 0; mt < 4; ++mt)
#pragma unroll
      for (int nt = 0; nt < 4; ++nt)
        acc[mt][nt] = mfma16(af[mt], bf[nt], acc[mt][nt]);
  }

  const float sc = (bn < qcols) ? 0.18033688011112043f : 1.0f;
#pragma unroll
  for (int mt = 0; mt < 4; ++mt) {
#pragma unroll
    for (int nt = 0; nt < 4; ++nt) {
      int gc = bn + wn + nt * 16 + l15;
      float bv = bias[gc];
#pragma unroll
      for (int r = 0; r < 4; ++r) {
        int gr = bm + wm + mt * 16 + quad * 4 + r;
        float val = (acc[mt][nt][r] + bv) * sc;
        if constexpr (C_BF16)
          ((__bf16*)Cv)[(size_t)gr * N + gc] = (__bf16)val;
        else
          ((float*)Cv)[(size_t)gr * N + gc] = val;
      }
    }
  }
}

// exp + (optional causal mask) + deferred-l + packed P store in pi-layout.
template <bool MASK>
__device__ __forceinline__ void softmax_block(f32x4 (&s)[2][4],
                                              float (&lsum)[2][4],
                                              __bf16* __restrict__ psw,
                                              int kv0, int qrow_base, int quad,
                                              int l15) {
#pragma unroll
  for (int mt = 0; mt < 2; ++mt) {
#pragma unroll
    for (int r = 0; r < 4; ++r) {
      int prow = mt * 16 + quad * 4 + r;
      float p[4];
#pragma unroll
      for (int nt = 0; nt < 4; ++nt) {
        p[nt] = fast_exp2(s[mt][nt][r]);  // scale pre-folded into Q
        if constexpr (MASK) {
          if ((kv0 + nt * 16 + l15) > (qrow_base + prow)) p[nt] = 0.f;
        }
      }
      lsum[mt][r] += (p[0] + p[1]) + (p[2] + p[3]);
      uint2 w = {pack_bf16(p[0], p[1]), pack_bf16(p[2], p[3])};
      int o = ((l15 >> 1) ^ (prow & 7)) & 7;
      *(uint2*)(psw + prow * 64 + o * 8 + 4 * (l15 & 1)) = w;
    }
  }
}

// Flash attention, causal. qkv: (B*T, 3072) bf16 (Q pre-scaled by log2e/8);
// out: (B*T, 1024) bf16. Grid (64 bh, 8 pb) bh-fastest (KV L2-resident per
// XCD). Block 256 = 4 waves, BQ=128, BKV=64; phases {pb, 15-pb} -> 34 iters.
// P/V k-index permuted by pi(k)=4*(k&15)+(k>>4) -> packed P stores; XOR
// octet swizzles keep LDS bank-uniform. No-max softmax, deferred l.
__global__ __launch_bounds__(256) void attn_kernel(
    const __bf16* __restrict__ qkv, __bf16* __restrict__ out) {
  constexpr int T = 2048, C3 = 3072;
  constexpr int KVSTEP = 64 * C3;
  __shared__ __bf16 Ks[2][64 * 64];  // [kv][d]
  __shared__ __bf16 Vt[2][64 * 64];  // [d][pi(kv)]
  __shared__ __bf16 Ps[4][32 * 64];  // per-wave [qrow][pi(kv)]

  const int tid = threadIdx.x;
  const int wid = tid >> 6;
  const int lane = tid & 63;
  const int l15 = lane & 15;
  const int quad = lane >> 4;
  const int bh = blockIdx.x;  // 0..63 (fastest -> same XCD per bh)
  const int pb = blockIdx.y;  // 0..7
  const int b = bh >> 4, h = bh & 15;
  const size_t rowbase = (size_t)b * T;

  const int kr = tid >> 3;  // K staging: rows kr, kr+32
  const int kc = tid & 7;   // d-octet
  const int vj = tid >> 4;  // V staging: rows vj+16i -> pi-cols 4vj+i
  const int vn = tid & 15;  // d-nibble

  const __bf16* gk_base = qkv + rowbase * C3 + 1024 + h * 64 + kr * C3 + kc * 8;
  const __bf16* gv_base = qkv + rowbase * C3 + 2048 + h * 64 + vj * C3 + vn * 4;

#pragma unroll 1
  for (int phase = 0; phase < 2; ++phase) {
    const int qp = phase == 0 ? pb : 15 - pb;
    const int q0 = qp * 128;
    const int ntiles = 2 * qp + 2;
    const int qrow_base = q0 + wid * 32;

    bf16x8 qf[2][2];
#pragma unroll
    for (int mt = 0; mt < 2; ++mt)
#pragma unroll
      for (int ksi = 0; ksi < 2; ++ksi)
        qf[mt][ksi] = *(const bf16x8*)(
            qkv + (rowbase + qrow_base + mt * 16 + l15) * C3 + h * 64 +
            ksi * 32 + quad * 8);

    f32x4 acc[2][4] = {};
    float lsum[2][4] = {};

    const __bf16* gk = gk_base;
    const __bf16* gv = gv_base;

    // prefetch tile 0
    bf16x8 kreg[2];
    bf16x4 vreg[4];
    kreg[0] = *(const bf16x8*)(gk);
    kreg[1] = *(const bf16x8*)(gk + 32 * C3);
#pragma unroll
    for (int i = 0; i < 4; ++i)
      vreg[i] = *(const bf16x4*)(gv + i * 16 * C3);

    __syncthreads();  // previous phase's readers done

    for (int j = 0; j < ntiles; ++j) {
      __bf16* ksb = Ks[j & 1];
      __bf16* vtb = Vt[j & 1];
      // ---- LDS store of prefetched tile ----
#pragma unroll
      for (int p = 0; p < 2; ++p) {
        int r = p * 32 + kr;
        *(bf16x8*)(ksb + r * 64 + ((kc ^ (r & 7)) * 8)) = kreg[p];
      }
#pragma unroll
      for (int dd = 0; dd < 4; ++dd) {
        int d = 4 * vn + dd;
        bf16x4 t = {vreg[0][dd], vreg[1][dd], vreg[2][dd], vreg[3][dd]};
        int o = ((vj >> 1) ^ (d & 7) ^ (d >> 3)) & 7;
        *(bf16x4*)(vtb + d * 64 + o * 8 + 4 * (vj & 1)) = t;
      }
      // ---- prefetch next tile (strength-reduced pointers) ----
      if (j + 1 < ntiles) {
        gk += KVSTEP;
        gv += KVSTEP;
        kreg[0] = *(const bf16x8*)(gk);
        kreg[1] = *(const bf16x8*)(gk + 32 * C3);
#pragma unroll
        for (int i = 0; i < 4; ++i)
          vreg[i] = *(const bf16x4*)(gv + i * 16 * C3);
      }
      __syncthreads();

      const int kv0 = j * 64;
      // ---- S = Q K^T ----
      f32x4 s[2][4] = {};
#pragma unroll
      for (int nt = 0; nt < 4; ++nt) {
        int krow = nt * 16 + l15;
#pragma unroll
        for (int ksi = 0; ksi < 2; ++ksi) {
          bf16x8 kf = *(const bf16x8*)(
              ksb + krow * 64 + (((4 * ksi + quad) ^ (l15 & 7)) * 8));
#pragma unroll
          for (int mt = 0; mt < 2; ++mt)
            s[mt][nt] = mfma16(qf[mt][ksi], kf, s[mt][nt]);
        }
      }
      // ---- softmax: wave-uniform branch keeps hot path mask-free ----
      if ((kv0 + 63) > qrow_base)
        softmax_block<true>(s, lsum, Ps[wid], kv0, qrow_base, quad, l15);
      else
        softmax_block<false>(s, lsum, Ps[wid], kv0, qrow_base, quad, l15);

      // ---- O += P V (per-wave Ps: no barrier) ----
#pragma unroll
      for (int ksi = 0; ksi < 2; ++ksi) {
        bf16x8 pf[2];
#pragma unroll
        for (int mt = 0; mt < 2; ++mt) {
          int prow = mt * 16 + l15;
          pf[mt] = *(const bf16x8*)(
              Ps[wid] + prow * 64 + (((4 * ksi + quad) ^ (l15 & 7)) * 8));
        }
#pragma unroll
        for (int ntv = 0; ntv < 4; ++ntv) {
          int d = ntv * 16 + l15;
          int o = ((4 * ksi + quad) ^ (d & 7) ^ (d >> 3)) & 7;
          bf16x8 vf = *(const bf16x8*)(vtb + d * 64 + o * 8);
#pragma unroll
          for (int mt = 0; mt < 2; ++mt)
            acc[mt][ntv] = mfma16(pf[mt], vf, acc[mt][ntv]);
        }
      }
    }

    // ---- phase epilogue: reduce l, normalize, store ----
#pragma unroll
    for (int mt = 0; mt < 2; ++mt)
#pragma unroll
      for (int r = 0; r < 4; ++r) {
        float l = lsum[mt][r];
        l += __shfl_xor(l, 1);
        l += __shfl_xor(l, 2);
        l += __shfl_xor(l, 4);
        l += __shfl_xor(l, 8);
        float inv = 1.0f / l;
        int row = qrow_base + mt * 16 + quad * 4 + r;
        size_t ob = (rowbase + row) * 1024 + h * 64;
#pragma unroll
        for (int ntv = 0; ntv < 4; ++ntv)
          out[ob + ntv * 16 + l15] = (__bf16)(acc[mt][ntv][r] * inv);
      }
  }
}

extern "C" void kernel_launch(void* const* d_in, const int* in_sizes, int n_in,
                              void* d_out, int out_size, void* d_ws,
                              size_t ws_size, hipStream_t stream) {
  const float* x = (const float*)d_in[0];
  const float* qkv_w = (const float*)d_in[1];
  const float* qkv_b = (const float*)d_in[2];
  const float* out_w = (const float*)d_in[3];
  const float* out_b = (const float*)d_in[4];
  float* out = (float*)d_out;

  __bf16* qkv_ws = (__bf16*)d_ws;                  // 8192*3072
  __bf16* attn_ws = qkv_ws + (size_t)8192 * 3072;  // 8192*1024
  __bf16* xb = attn_ws + (size_t)8192 * 1024;      // 8192*1024
  __bf16* wqb = xb + (size_t)8192 * 1024;          // 3072*1024
  __bf16* wob = wqb + (size_t)3072 * 1024;         // 1024*1024

  convert3<<<6144, 256, 0, stream>>>(x, qkv_w, out_w, xb, wqb, wob);
  gemm_bt<true><<<dim3(24, 64), 256, 0, stream>>>(xb, wqb, qkv_b, qkv_ws,
                                                  8192, 3072, 1024, 1024);
  attn_kernel<<<dim3(64, 8), 256, 0, stream>>>(qkv_ws, attn_ws);
  gemm_bt<false><<<dim3(8, 64), 256, 0, stream>>>(attn_ws, wob, out_b, out,
                                                  8192, 1024, 1024, 0);
}

// Round 6
// 243.282 us; speedup vs baseline: 1.4498x; 1.0112x over previous
//
#include <hip/hip_runtime.h>

typedef __bf16 bf16x8 __attribute__((ext_vector_type(8)));
typedef __bf16 bf16x4 __attribute__((ext_vector_type(4)));
typedef float f32x4 __attribute__((ext_vector_type(4)));

typedef const __attribute__((address_space(1))) void* gptr_t;
typedef __attribute__((address_space(3))) void* lptr_t;

__device__ __forceinline__ f32x4 mfma16(bf16x8 a, bf16x8 b, f32x4 c) {
  return __builtin_amdgcn_mfma_f32_16x16x32_bf16(a, b, c, 0, 0, 0);
}

__device__ __forceinline__ void load_lds16(const __bf16* g, __bf16* l) {
  __builtin_amdgcn_global_load_lds((gptr_t)g, (lptr_t)l, 16, 0, 0);
}

__device__ __forceinline__ float fast_exp2(float x) {
#if __has_builtin(__builtin_amdgcn_exp2f)
  return __builtin_amdgcn_exp2f(x);  // raw v_exp_f32
#else
  return exp2f(x);
#endif
}

// round-to-nearest(+away) f32->bf16 for two values, packed into one dword
__device__ __forceinline__ unsigned pack_bf16(float f0, float f1) {
  unsigned u0 = __builtin_bit_cast(unsigned, f0) + 0x8000u;
  unsigned u1 = __builtin_bit_cast(unsigned, f1) + 0x8000u;
  return __builtin_amdgcn_perm(u1, u0, 0x07060302);
}

// ---- fp32 -> bf16 pre-convert: x (4096 blks), qkv_w (1536), out_w (512) ----
__global__ __launch_bounds__(256) void convert3(
    const float* __restrict__ x, const float* __restrict__ w1,
    const float* __restrict__ w2, __bf16* __restrict__ xb,
    __bf16* __restrict__ w1b, __bf16* __restrict__ w2b) {
  int bid = blockIdx.x;
  const float* src;
  __bf16* dst;
  int base;
  if (bid < 4096) {
    src = x; dst = xb; base = bid;
  } else if (bid < 5632) {
    src = w1; dst = w1b; base = bid - 4096;
  } else {
    src = w2; dst = w2b; base = bid - 5632;
  }
  size_t off = (size_t)base * 2048 + threadIdx.x * 8;
  float4 v0 = *(const float4*)(src + off);
  float4 v1 = *(const float4*)(src + off + 4);
  bf16x8 o = {(__bf16)v0.x, (__bf16)v0.y, (__bf16)v0.z, (__bf16)v0.w,
              (__bf16)v1.x, (__bf16)v1.y, (__bf16)v1.z, (__bf16)v1.w};
  *(bf16x8*)(dst + off) = o;
}

// C[M][N] = A[M][K] @ B[N][K]^T + bias[N]; A,B bf16; C bf16 or fp32.
// m97 pattern + chunk-swizzled staging: lane fetches global chunk
// c ^ ((r>>1)&3) so the forced lane*16 LDS image is chunk-permuted; the
// fragment read offset quad ^ ((l15>>1)&3) makes every quad-phase of the
// ds_read_b128 hit 4 distinct bank groups (2-way max = free).
template <bool C_BF16>
__global__ __launch_bounds__(256) void gemm_bt(
    const __bf16* __restrict__ A, const __bf16* __restrict__ B,
    const float* __restrict__ bias, void* __restrict__ Cv, int M, int N,
    int K, int qcols) {
  __shared__ __bf16 As[2][128 * 32];
  __shared__ __bf16 Bs[2][128 * 32];

  const int tid = threadIdx.x;
  const int wid = tid >> 6;
  const int lane = tid & 63;
  const int l15 = lane & 15;
  const int quad = lane >> 4;
  const int bm = blockIdx.y * 128;
  const int bn = blockIdx.x * 128;
  const int wm = (wid & 1) * 64;
  const int wn = (wid >> 1) * 64;

  // staging: lane l -> row wid*16+(l>>2), global chunk (l&3)^((l>>3)&3)
  const int srow = wid * 16 + (lane >> 2);
  const int schunk = ((lane & 3) ^ ((lane >> 3) & 3)) * 8;
  const __bf16* gA = A + (size_t)(bm + srow) * K + schunk;
  const __bf16* gB = B + (size_t)(bn + srow) * K + schunk;
  const int ldsoff = wid * 16 * 32;  // wave-uniform

  // fragment-read chunk slot (loop-invariant; wm/i*16 vanish mod 4 after >>1)
  const int fsl = (quad ^ ((l15 >> 1) & 3)) * 8;

  f32x4 acc[4][4] = {};

  load_lds16(gA, &As[0][ldsoff]);
  load_lds16(gA + (size_t)64 * K, &As[0][64 * 32 + ldsoff]);
  load_lds16(gB, &Bs[0][ldsoff]);
  load_lds16(gB + (size_t)64 * K, &Bs[0][64 * 32 + ldsoff]);

  const int niter = K >> 5;
  for (int it = 0; it < niter; ++it) {
    const int cur = it & 1;
    __syncthreads();
    if (it + 1 < niter) {
      int k0 = (it + 1) << 5;
      load_lds16(gA + k0, &As[1 - cur][ldsoff]);
      load_lds16(gA + k0 + (size_t)64 * K, &As[1 - cur][64 * 32 + ldsoff]);
      load_lds16(gB + k0, &Bs[1 - cur][ldsoff]);
      load_lds16(gB + k0 + (size_t)64 * K, &Bs[1 - cur][64 * 32 + ldsoff]);
    }
    bf16x8 af[4], bf[4];
#pragma unroll
    for (int i = 0; i < 4; ++i)
      af[i] = *(const bf16x8*)(&As[cur][(wm + i * 16 + l15) * 32 + fsl]);
#pragma unroll
    for (int i = 0; i < 4; ++i)
      bf[i] = *(const bf16x8*)(&Bs[cur][(wn + i * 16 + l15) * 32 + fsl]);
#pragma unroll
    for (int mt = 0; mt < 4; ++mt)
#pragma unroll
      for (int nt = 0; nt < 4; ++nt)
        acc[mt][nt] = mfma16(af[mt], bf[nt], acc[mt][nt]);
  }

  const float sc = (bn < qcols) ? 0.18033688011112043f : 1.0f;
#pragma unroll
  for (int mt = 0; mt < 4; ++mt) {
#pragma unroll
    for (int nt = 0; nt < 4; ++nt) {
      int gc = bn + wn + nt * 16 + l15;
      float bv = bias[gc];
#pragma unroll
      for (int r = 0; r < 4; ++r) {
        int gr = bm + wm + mt * 16 + quad * 4 + r;
        float val = (acc[mt][nt][r] + bv) * sc;
        if constexpr (C_BF16)
          ((__bf16*)Cv)[(size_t)gr * N + gc] = (__bf16)val;
        else
          ((float*)Cv)[(size_t)gr * N + gc] = val;
      }
    }
  }
}

// exp + (optional causal mask) + deferred-l + packed P store in pi-layout.
template <bool MASK>
__device__ __forceinline__ void softmax_block(f32x4 (&s)[2][4],
                                              float (&lsum)[2][4],
                                              __bf16* __restrict__ psw,
                                              int kv0, int qrow_base, int quad,
                                              int l15) {
#pragma unroll
  for (int mt = 0; mt < 2; ++mt) {
#pragma unroll
    for (int r = 0; r < 4; ++r) {
      int prow = mt * 16 + quad * 4 + r;
      float p[4];
#pragma unroll
      for (int nt = 0; nt < 4; ++nt) {
        p[nt] = fast_exp2(s[mt][nt][r]);  // scale pre-folded into Q
        if constexpr (MASK) {
          if ((kv0 + nt * 16 + l15) > (qrow_base + prow)) p[nt] = 0.f;
        }
      }
      lsum[mt][r] += (p[0] + p[1]) + (p[2] + p[3]);
      uint2 w = {pack_bf16(p[0], p[1]), pack_bf16(p[2], p[3])};
      int o = ((l15 >> 1) ^ (prow & 7)) & 7;
      *(uint2*)(psw + prow * 64 + o * 8 + 4 * (l15 & 1)) = w;
    }
  }
}

// Flash attention, causal. qkv: (B*T, 3072) bf16 (Q pre-scaled by log2e/8);
// out: (B*T, 1024) bf16. Grid (64 bh, 8 pb) bh-fastest (KV L2-resident per
// XCD). Block 256 = 4 waves, BQ=128, BKV=64; phases {pb, 15-pb} -> 34 iters.
// P/V k-index permuted by pi(k)=4*(k&15)+(k>>4) -> packed P stores; XOR
// octet swizzles keep LDS bank-uniform. No-max softmax, deferred l.
// All LDS fragment offsets precomputed outside the kv-loop.
__global__ __launch_bounds__(256) void attn_kernel(
    const __bf16* __restrict__ qkv, __bf16* __restrict__ out) {
  constexpr int T = 2048, C3 = 3072;
  constexpr int KVSTEP = 64 * C3;
  __shared__ __bf16 Ks[2][64 * 64];  // [kv][d]
  __shared__ __bf16 Vt[2][64 * 64];  // [d][pi(kv)]
  __shared__ __bf16 Ps[4][32 * 64];  // per-wave [qrow][pi(kv)]

  const int tid = threadIdx.x;
  const int wid = tid >> 6;
  const int lane = tid & 63;
  const int l15 = lane & 15;
  const int quad = lane >> 4;
  const int bh = blockIdx.x;  // 0..63 (fastest -> same XCD per bh)
  const int pb = blockIdx.y;  // 0..7
  const int b = bh >> 4, h = bh & 15;
  const size_t rowbase = (size_t)b * T;

  const int kr = tid >> 3;  // K staging: rows kr, kr+32
  const int kc = tid & 7;   // d-octet
  const int vj = tid >> 4;  // V staging: rows vj+16i -> pi-cols 4vj+i
  const int vn = tid & 15;  // d-nibble

  const __bf16* gk_base = qkv + rowbase * C3 + 1024 + h * 64 + kr * C3 + kc * 8;
  const __bf16* gv_base = qkv + rowbase * C3 + 2048 + h * 64 + vj * C3 + vn * 4;

  // ---- loop-invariant LDS offsets (elements) ----
  int ks_st0 = kr * 64 + ((kc ^ (kr & 7)) * 8);            // K store row kr
  int ks_st1 = (kr + 32) * 64 + ((kc ^ ((kr + 32) & 7)) * 8);
  int vt_st[4];
#pragma unroll
  for (int dd = 0; dd < 4; ++dd) {
    int d = 4 * vn + dd;
    vt_st[dd] = d * 64 + ((((vj >> 1) ^ (d & 7) ^ (d >> 3)) & 7) * 8) +
                4 * (vj & 1);
  }
  int kf_off[4][2];
#pragma unroll
  for (int nt = 0; nt < 4; ++nt)
#pragma unroll
    for (int ksi = 0; ksi < 2; ++ksi)
      kf_off[nt][ksi] =
          (nt * 16 + l15) * 64 + (((4 * ksi + quad) ^ (l15 & 7)) * 8);
  int pf_off[2][2];
#pragma unroll
  for (int mt = 0; mt < 2; ++mt)
#pragma unroll
    for (int ksi = 0; ksi < 2; ++ksi)
      pf_off[mt][ksi] =
          (mt * 16 + l15) * 64 + (((4 * ksi + quad) ^ (l15 & 7)) * 8);
  int vf_off[4][2];
#pragma unroll
  for (int ntv = 0; ntv < 4; ++ntv)
#pragma unroll
    for (int ksi = 0; ksi < 2; ++ksi) {
      int d = ntv * 16 + l15;
      vf_off[ntv][ksi] =
          d * 64 + ((((4 * ksi + quad) ^ (d & 7) ^ (d >> 3)) & 7) * 8);
    }

#pragma unroll 1
  for (int phase = 0; phase < 2; ++phase) {
    const int qp = phase == 0 ? pb : 15 - pb;
    const int q0 = qp * 128;
    const int ntiles = 2 * qp + 2;
    const int qrow_base = q0 + wid * 32;

    bf16x8 qf[2][2];
#pragma unroll
    for (int mt = 0; mt < 2; ++mt)
#pragma unroll
      for (int ksi = 0; ksi < 2; ++ksi)
        qf[mt][ksi] = *(const bf16x8*)(
            qkv + (rowbase + qrow_base + mt * 16 + l15) * C3 + h * 64 +
            ksi * 32 + quad * 8);

    f32x4 acc[2][4] = {};
    float lsum[2][4] = {};

    const __bf16* gk = gk_base;
    const __bf16* gv = gv_base;

    bf16x8 kreg[2];
    bf16x4 vreg[4];
    kreg[0] = *(const bf16x8*)(gk);
    kreg[1] = *(const bf16x8*)(gk + 32 * C3);
#pragma unroll
    for (int i = 0; i < 4; ++i)
      vreg[i] = *(const bf16x4*)(gv + i * 16 * C3);

    __syncthreads();  // previous phase's readers done

    for (int j = 0; j < ntiles; ++j) {
      __bf16* ksb = Ks[j & 1];
      __bf16* vtb = Vt[j & 1];
      *(bf16x8*)(ksb + ks_st0) = kreg[0];
      *(bf16x8*)(ksb + ks_st1) = kreg[1];
#pragma unroll
      for (int dd = 0; dd < 4; ++dd) {
        bf16x4 t = {vreg[0][dd], vreg[1][dd], vreg[2][dd], vreg[3][dd]};
        *(bf16x4*)(vtb + vt_st[dd]) = t;
      }
      if (j + 1 < ntiles) {
        gk += KVSTEP;
        gv += KVSTEP;
        kreg[0] = *(const bf16x8*)(gk);
        kreg[1] = *(const bf16x8*)(gk + 32 * C3);
#pragma unroll
        for (int i = 0; i < 4; ++i)
          vreg[i] = *(const bf16x4*)(gv + i * 16 * C3);
      }
      __syncthreads();

      const int kv0 = j * 64;
      // ---- S = Q K^T ----
      f32x4 s[2][4] = {};
#pragma unroll
      for (int nt = 0; nt < 4; ++nt) {
#pragma unroll
        for (int ksi = 0; ksi < 2; ++ksi) {
          bf16x8 kf = *(const bf16x8*)(ksb + kf_off[nt][ksi]);
#pragma unroll
          for (int mt = 0; mt < 2; ++mt)
            s[mt][nt] = mfma16(qf[mt][ksi], kf, s[mt][nt]);
        }
      }
      // ---- softmax (wave-uniform mask branch) ----
      if ((kv0 + 63) > qrow_base)
        softmax_block<true>(s, lsum, Ps[wid], kv0, qrow_base, quad, l15);
      else
        softmax_block<false>(s, lsum, Ps[wid], kv0, qrow_base, quad, l15);

      // ---- O += P V (per-wave Ps: no barrier) ----
#pragma unroll
      for (int ksi = 0; ksi < 2; ++ksi) {
        bf16x8 pf[2];
#pragma unroll
        for (int mt = 0; mt < 2; ++mt)
          pf[mt] = *(const bf16x8*)(Ps[wid] + pf_off[mt][ksi]);
#pragma unroll
        for (int ntv = 0; ntv < 4; ++ntv) {
          bf16x8 vf = *(const bf16x8*)(vtb + vf_off[ntv][ksi]);
#pragma unroll
          for (int mt = 0; mt < 2; ++mt)
            acc[mt][ntv] = mfma16(pf[mt], vf, acc[mt][ntv]);
        }
      }
    }

    // ---- phase epilogue: reduce l, normalize, store ----
#pragma unroll
    for (int mt = 0; mt < 2; ++mt)
#pragma unroll
      for (int r = 0; r < 4; ++r) {
        float l = lsum[mt][r];
        l += __shfl_xor(l, 1);
        l += __shfl_xor(l, 2);
        l += __shfl_xor(l, 4);
        l += __shfl_xor(l, 8);
        float inv = 1.0f / l;
        int row = qrow_base + mt * 16 + quad * 4 + r;
        size_t ob = (rowbase + row) * 1024 + h * 64;
#pragma unroll
        for (int ntv = 0; ntv < 4; ++ntv)
          out[ob + ntv * 16 + l15] = (__bf16)(acc[mt][ntv][r] * inv);
      }
  }
}

extern "C" void kernel_launch(void* const* d_in, const int* in_sizes, int n_in,
                              void* d_out, int out_size, void* d_ws,
                              size_t ws_size, hipStream_t stream) {
  const float* x = (const float*)d_in[0];
  const float* qkv_w = (const float*)d_in[1];
  const float* qkv_b = (const float*)d_in[2];
  const float* out_w = (const float*)d_in[3];
  const float* out_b = (const float*)d_in[4];
  float* out = (float*)d_out;

  __bf16* qkv_ws = (__bf16*)d_ws;                  // 8192*3072
  __bf16* attn_ws = qkv_ws + (size_t)8192 * 3072;  // 8192*1024
  __bf16* xb = attn_ws + (size_t)8192 * 1024;      // 8192*1024
  __bf16* wqb = xb + (size_t)8192 * 1024;          // 3072*1024
  __bf16* wob = wqb + (size_t)3072 * 1024;         // 1024*1024

  convert3<<<6144, 256, 0, stream>>>(x, qkv_w, out_w, xb, wqb, wob);
  gemm_bt<true><<<dim3(24, 64), 256, 0, stream>>>(xb, wqb, qkv_b, qkv_ws,
                                                  8192, 3072, 1024, 1024);
  attn_kernel<<<dim3(64, 8), 256, 0, stream>>>(qkv_ws, attn_ws);
  gemm_bt<false><<<dim3(8, 64), 256, 0, stream>>>(attn_ws, wob, out_b, out,
                                                  8192, 1024, 1024, 0);
}